// Round 2
// baseline (1007.161 us; speedup 1.0000x reference)
//
#include <hip/hip_runtime.h>

// Shapes (fixed by the problem)
#define S_DIM 256
#define B_DIM 32
#define T_DIM 24
#define D_DIM 512

typedef short short8 __attribute__((ext_vector_type(8)));          // bf16x8 MFMA frag
typedef unsigned short ushort8 __attribute__((ext_vector_type(8)));
typedef unsigned short ushort4v __attribute__((ext_vector_type(4)));
typedef float float4v __attribute__((ext_vector_type(4)));

__device__ __forceinline__ float bf2f(unsigned short u) {
  union { unsigned int i; float f; } v; v.i = ((unsigned int)u) << 16; return v.f;
}
__device__ __forceinline__ unsigned short f2bf(float f) {
  union { float f; unsigned int i; } v; v.f = f;
  unsigned int i = v.i;
  return (unsigned short)((i + 0x7fffu + ((i >> 16) & 1u)) >> 16);  // RNE
}
// tanh(x) = 1 - 2/(exp2(2*log2e*x)+1); saturates correctly for |x| large.
__device__ __forceinline__ float tanh_fast(float x) {
  float p = __builtin_amdgcn_exp2f(x * 2.885390082f);
  return 1.f - 2.f * __builtin_amdgcn_rcpf(1.f + p);
}

__device__ __forceinline__ void gload_lds16(const void* g, void* l) {
  __builtin_amdgcn_global_load_lds(
      (const __attribute__((address_space(1))) void*)g,
      (__attribute__((address_space(3))) void*)l, 16, 0, 0);
}

// ---------------------------------------------------------------------------
// fp32 -> bf16 pre-pass for the 7 GEMM operands.
// float4-index segments: ctx[1048576] img[1048576] qo[98304] fc1w/fc2w/dmw/qmw[65536 each]
// total = 2457600 float4s = 9600 blocks x 256 threads, exactly.
// ---------------------------------------------------------------------------
__global__ __launch_bounds__(256)
void cvt_kernel(const float* __restrict__ s0, const float* __restrict__ s1,
                const float* __restrict__ s2, const float* __restrict__ s3,
                const float* __restrict__ s4, const float* __restrict__ s5,
                const float* __restrict__ s6,
                unsigned short* __restrict__ d0, unsigned short* __restrict__ d1,
                unsigned short* __restrict__ d2, unsigned short* __restrict__ d3,
                unsigned short* __restrict__ d4, unsigned short* __restrict__ d5,
                unsigned short* __restrict__ d6)
{
  const int idx = blockIdx.x * 256 + threadIdx.x;
  const float* s; unsigned short* d; int off;
  if (idx < 2097152) {
    off = idx & 1048575;
    if (idx < 1048576) { s = s0; d = d0; } else { s = s1; d = d1; }
  } else if (idx < 2195456) {
    off = idx - 2097152; s = s2; d = d2;
  } else {
    const int k = (idx - 2195456) >> 16;
    off = (idx - 2195456) & 65535;
    switch (k) {
      case 0:  s = s3; d = d3; break;
      case 1:  s = s4; d = d4; break;
      case 2:  s = s5; d = d5; break;
      default: s = s6; d = d6; break;
    }
  }
  const float4v v = ((const float4v*)s)[off];
  ushort4v u;
  u[0] = f2bf(v[0]); u[1] = f2bf(v[1]); u[2] = f2bf(v[2]); u[3] = f2bf(v[3]);
  ((ushort4v*)d)[off] = u;
}

// ---------------------------------------------------------------------------
// NT GEMM: out[m,e] = sum_k A[m,k]*W[e,k] (+bias1[e]+bias2[e], fp32 biases)
// A,W bf16 row-major. PERMUTE: out row = (m&31)*256 + (m>>5)  ((s,b) -> [b,s]).
// m97 recipe: 128x128 tile, BK=32, 4 waves, global_load_lds width-16.
// ---------------------------------------------------------------------------
template<bool DUAL, bool OUT_BF16, bool PERMUTE>
__global__ __launch_bounds__(256)
void gemm_nt(const unsigned short* __restrict__ A1,
             const unsigned short* __restrict__ A2,
             const unsigned short* __restrict__ W1,
             const unsigned short* __restrict__ W2,
             const float* __restrict__ bias1,
             const float* __restrict__ bias2,
             void* __restrict__ out)
{
  __shared__ unsigned short At[128 * 32] __attribute__((aligned(16)));
  __shared__ unsigned short Bt[128 * 32] __attribute__((aligned(16)));

  const int tid  = threadIdx.x;
  const int wid  = tid >> 6;
  const int lane = tid & 63;
  const int bm = blockIdx.x, bn = blockIdx.y;
  const int wm = (wid & 1) * 64, wn = (wid >> 1) * 64;

  float4v acc[4][4];
#pragma unroll
  for (int i = 0; i < 4; ++i)
#pragma unroll
    for (int jj = 0; jj < 4; ++jj) acc[i][jj] = (float4v){0.f, 0.f, 0.f, 0.f};

  const int NK = DUAL ? 32 : 16;
  for (int it = 0; it < NK; ++it) {
    const int kk = it * 32;
    const unsigned short* As = A1;
    const unsigned short* Ws = W1;
    int ks = kk;
    if (DUAL && kk >= 512) { As = A2; Ws = W2; ks = kk - 512; }

    __syncthreads();   // previous iter's LDS reads done before overwrite
#pragma unroll
    for (int i = 0; i < 2; ++i) {
      const int lrow = wid * 32 + i * 16 + (lane >> 2);
      const int kc = (lane & 3) * 8;
      gload_lds16(As + (size_t)(bm * 128 + lrow) * 512 + ks + kc,
                  &At[(wid * 32 + i * 16) * 32]);       // wave-uniform LDS base
      gload_lds16(Ws + (size_t)(bn * 128 + lrow) * 512 + ks + kc,
                  &Bt[(wid * 32 + i * 16) * 32]);
    }
    __syncthreads();   // vmcnt(0) drain + barrier

    short8 fa[4], fb[4];
#pragma unroll
    for (int mi = 0; mi < 4; ++mi)
      fa[mi] = *(const short8*)&At[(wm + mi * 16 + (lane & 15)) * 32 + (lane >> 4) * 8];
#pragma unroll
    for (int ni = 0; ni < 4; ++ni)
      fb[ni] = *(const short8*)&Bt[(wn + ni * 16 + (lane & 15)) * 32 + (lane >> 4) * 8];
#pragma unroll
    for (int mi = 0; mi < 4; ++mi)
#pragma unroll
      for (int ni = 0; ni < 4; ++ni)
        acc[mi][ni] = __builtin_amdgcn_mfma_f32_16x16x32_bf16(fa[mi], fb[ni], acc[mi][ni], 0, 0, 0);
  }

  // epilogue: C/D layout col = lane&15, row = (lane>>4)*4 + reg
#pragma unroll
  for (int mi = 0; mi < 4; ++mi) {
    const int row0 = wm + mi * 16 + (lane >> 4) * 4;
#pragma unroll
    for (int ni = 0; ni < 4; ++ni) {
      const int col = bn * 128 + wn + ni * 16 + (lane & 15);
      float bsum = 0.f;
      if (bias1) bsum += bias1[col];
      if (bias2) bsum += bias2[col];
#pragma unroll
      for (int i = 0; i < 4; ++i) {
        const int m = bm * 128 + row0 + i;
        const int orow = PERMUTE ? ((m & 31) * 256 + (m >> 5)) : m;
        const float v = acc[mi][ni][i] + bsum;
        if (OUT_BF16) ((unsigned short*)out)[(size_t)orow * 512 + col] = f2bf(v);
        else          ((float*)out)[(size_t)orow * 512 + col] = v;
      }
    }
  }
}

// ---------------------------------------------------------------------------
// Scan kernel: 256 blocks = 32 b-groups x 8 blocks. Block (b,j):
//  - owns e-chunk [64j,64j+64) for the rm/rr matvecs (bf16 weights in VGPRs)
//  - owns s-chunk [32j,32j+32) for logits/softmax partials
// Max-free softmax => 2 per-b syncs per step (monotone atomic counters).
// rrtB is double-buffered by t&1 (write at t+1 may overlap slow block's read at t).
// ---------------------------------------------------------------------------
__global__ __launch_bounds__(512)
void scan_kernel(const unsigned short* __restrict__ co,
                 const unsigned short* __restrict__ codm,
                 const float* __restrict__ qadd,
                 float* __restrict__ addB,
                 float* __restrict__ rrtB,   // [2][B][512]
                 float* __restrict__ denB,
                 float* __restrict__ pvecB,
                 unsigned int* __restrict__ cnt,
                 const float* __restrict__ ms_w,
                 const float* __restrict__ rm_w,
                 const float* __restrict__ rr_w,
                 const float* __restrict__ rr_b,
                 const float* __restrict__ qhs,
                 const float* __restrict__ rg_w,
                 const float* __restrict__ qg_w,
                 const float* __restrict__ rg_b,
                 const float* __restrict__ qg_b,
                 float* __restrict__ outg)
{
  __shared__ unsigned short scrS[32 * 520] __attribute__((aligned(16)));  // stage scratch, later cdS[32][512]
  __shared__ float rS[512];
  __shared__ float addS[512] __attribute__((aligned(16)));
  __shared__ float msS[512] __attribute__((aligned(16)));
  __shared__ float partS[512];
  __shared__ float partR[512];
  __shared__ float wS[32];
  __shared__ float rrbS[64];

  const int tid  = threadIdx.x;
  const int wid  = tid >> 6;   // 8 waves
  const int lane = tid & 63;
  const int b = blockIdx.x >> 3;
  const int j = blockIdx.x & 7;
  unsigned int* cntb = cnt + b * 16;   // 64B-spaced counters

  // ---- preload rm_w/rr_w rows [64j,64j+64) into VGPRs (bf16) via LDS bounce.
  // thread (wid,lane) ends holding W[e = 64j+lane][k = 64*wid + 8u + i].
  ushort8 rmp[8], rrp[8];
  for (int pass = 0; pass < 4; ++pass) {
    const float* Wsrc = (pass < 2) ? rm_w : rr_w;
    const int rbase = (pass & 1) * 32;
    for (int r = wid; r < 32; r += 8) {
      const float* src = &Wsrc[(size_t)(j * 64 + rbase + r) * 512 + lane * 8];
      float4v a = *(const float4v*)src;
      float4v c = *(const float4v*)(src + 4);
      ushort8 u8;
#pragma unroll
      for (int i = 0; i < 4; ++i) { u8[i] = f2bf(a[i]); u8[i + 4] = f2bf(c[i]); }
      *(ushort8*)&scrS[r * 520 + lane * 8] = u8;
    }
    __syncthreads();
    if ((lane >> 5) == (pass & 1)) {
      const int rloc = lane & 31;
#pragma unroll
      for (int u = 0; u < 8; ++u) {
        ushort8 v = *(const ushort8*)&scrS[rloc * 520 + wid * 64 + u * 8];
        if (pass < 2) rmp[u] = v; else rrp[u] = v;
      }
    }
    __syncthreads();
  }

  // ---- co_dm s-chunk into LDS (bf16, contiguous rows of 512)
  const size_t gbase = ((size_t)b * 256 + j * 32) * 512;
  for (int idx = tid; idx < 2048; idx += 512)
    *(ushort8*)&scrS[idx * 8] = *(const ushort8*)&codm[gbase + (size_t)idx * 8];
  const unsigned short* cdS = scrS;

  msS[tid] = ms_w[tid];
  if (tid < 64) rrbS[tid] = rr_b[j * 64 + tid];
  rS[tid] = 0.f;
  __syncthreads();

  for (int t = 0; t < T_DIM; ++t) {
    // ---------- matvec: add = r*rm^T (+qadd[t]), rrt = tanh(r*rr^T+rr_b)
    float am = 0.f, ar = 0.f;
#pragma unroll
    for (int u = 0; u < 8; ++u) {
      ushort8 wm8 = rmp[u], wr8 = rrp[u];
#pragma unroll
      for (int i2 = 0; i2 < 8; ++i2) {
        const float rv = rS[wid * 64 + u * 8 + i2];   // wave-uniform broadcast
        am = fmaf(rv, bf2f(wm8[i2]), am);
        ar = fmaf(rv, bf2f(wr8[i2]), ar);
      }
    }
    partS[wid * 64 + lane] = am;
    partR[wid * 64 + lane] = ar;
    __syncthreads();
    if (wid == 0) {
      float s = 0.f;
#pragma unroll
      for (int w2 = 0; w2 < 8; ++w2) s += partS[w2 * 64 + lane];
      s += qadd[((size_t)t * 32 + b) * 512 + j * 64 + lane];
      addB[b * 512 + j * 64 + lane] = s;
    } else if (wid == 1) {
      float s = 0.f;
#pragma unroll
      for (int w2 = 0; w2 < 8; ++w2) s += partR[w2 * 64 + lane];
      rrtB[(t & 1) * (B_DIM * 512) + b * 512 + j * 64 + lane] = tanh_fast(s + rrbS[lane]);
    }
    __syncthreads();
    if (tid == 0) {   // sync A: add/rrt chunks visible
      __threadfence();
      atomicAdd(cntb, 1u);
      const unsigned int tgt = 8u * (2u * (unsigned)t + 1u);
      while (__hip_atomic_load(cntb, __ATOMIC_ACQUIRE, __HIP_MEMORY_SCOPE_AGENT) < tgt)
        __builtin_amdgcn_s_sleep(1);
      __threadfence();
    }
    __syncthreads();

    // ---------- logits for s-chunk: rows sl = 4*wid..4*wid+3
    addS[tid] = addB[b * 512 + tid];
    __syncthreads();
#pragma unroll
    for (int q = 0; q < 4; ++q) {
      const int sl = wid * 4 + q;
      ushort8 cd8 = *(const ushort8*)&cdS[sl * 512 + lane * 8];
      float4v a0 = *(const float4v*)&addS[lane * 8];
      float4v a1 = *(const float4v*)&addS[lane * 8 + 4];
      float4v m0 = *(const float4v*)&msS[lane * 8];
      float4v m1 = *(const float4v*)&msS[lane * 8 + 4];
      float acc = 0.f;
#pragma unroll
      for (int i = 0; i < 4; ++i) {
        acc = fmaf(tanh_fast(bf2f(cd8[i]) + a0[i]), m0[i], acc);
        acc = fmaf(tanh_fast(bf2f(cd8[i + 4]) + a1[i]), m1[i], acc);
      }
#pragma unroll
      for (int off = 32; off > 0; off >>= 1) acc += __shfl_xor(acc, off, 64);
      if (lane == 0) wS[sl] = __builtin_amdgcn_exp2f(acc * 1.44269504f);  // exp(logit), max-free
    }
    __syncthreads();

    // ---------- weighted partials: pvec_j[e] = sum_{s chunk} w[s]*co[b,s,e]
    {
      float accv = 0.f;
#pragma unroll 8
      for (int sl = 0; sl < 32; ++sl)
        accv = fmaf(wS[sl], bf2f(co[gbase + (size_t)sl * 512 + tid]), accv);
      pvecB[((size_t)b * 8 + j) * 512 + tid] = accv;
      if (tid == 0) {
        float dsum = 0.f;
        for (int sl = 0; sl < 32; ++sl) dsum += wS[sl];
        denB[b * 8 + j] = dsum;
      }
    }
    __syncthreads();
    if (tid == 0) {   // sync B: pvec/den visible
      __threadfence();
      atomicAdd(cntb, 1u);
      const unsigned int tgt = 8u * (2u * (unsigned)t + 2u);
      while (__hip_atomic_load(cntb, __ATOMIC_ACQUIRE, __HIP_MEMORY_SCOPE_AGENT) < tgt)
        __builtin_amdgcn_s_sleep(1);
      __threadfence();
    }
    __syncthreads();

    // ---------- reconstruct r (replicated, identical across the 8 blocks)
    {
      float sum = 0.f;
#pragma unroll
      for (int jj = 0; jj < 8; ++jj) sum += pvecB[((size_t)b * 8 + jj) * 512 + tid];
      float den = 0.f;
#pragma unroll
      for (int jj = 0; jj < 8; ++jj) den += denB[b * 8 + jj];
      rS[tid] = sum * __builtin_amdgcn_rcpf(den) +
                rrtB[(t & 1) * (B_DIM * 512) + b * 512 + tid];
    }
    __syncthreads();
  }

  // ---------- g = r*rg^T + rg_b + qhs*qg^T + qg_b, e-chunk [64j,64j+64)
  addS[tid] = qhs[b * 512 + tid];
  __syncthreads();
  {
    const int e = j * 64 + lane;
    const float* rgp = rg_w + (size_t)e * 512 + wid * 64;
    const float* qgp = qg_w + (size_t)e * 512 + wid * 64;
    float acc = 0.f;
#pragma unroll
    for (int u = 0; u < 8; ++u) {
      float4v g0 = *(const float4v*)&rgp[u * 8];
      float4v g1 = *(const float4v*)&rgp[u * 8 + 4];
      float4v q0 = *(const float4v*)&qgp[u * 8];
      float4v q1 = *(const float4v*)&qgp[u * 8 + 4];
#pragma unroll
      for (int i2 = 0; i2 < 4; ++i2) {
        acc = fmaf(rS[wid * 64 + u * 8 + i2],     g0[i2], acc);
        acc = fmaf(rS[wid * 64 + u * 8 + 4 + i2], g1[i2], acc);
        acc = fmaf(addS[wid * 64 + u * 8 + i2],     q0[i2], acc);
        acc = fmaf(addS[wid * 64 + u * 8 + 4 + i2], q1[i2], acc);
      }
    }
    partS[wid * 64 + lane] = acc;
  }
  __syncthreads();
  if (wid == 0) {
    float s = 0.f;
#pragma unroll
    for (int w2 = 0; w2 < 8; ++w2) s += partS[w2 * 64 + lane];
    const int e = j * 64 + lane;
    s += rg_b[e] + qg_b[e];
    outg[b * 512 + e] = s;
  }
}

// ---------------------------------------------------------------------------
extern "C" void kernel_launch(void* const* d_in, const int* in_sizes, int n_in,
                              void* d_out, int out_size, void* d_ws, size_t ws_size,
                              hipStream_t stream)
{
  (void)in_sizes; (void)n_in; (void)out_size; (void)ws_size;
  const float* ctx  = (const float*)d_in[0];
  const float* qo   = (const float*)d_in[2];
  const float* qhs  = (const float*)d_in[3];
  const float* img  = (const float*)d_in[4];
  const float* fc1w = (const float*)d_in[6];
  const float* fc1b = (const float*)d_in[7];
  const float* fc2w = (const float*)d_in[8];
  const float* fc2b = (const float*)d_in[9];
  const float* dmw  = (const float*)d_in[10];
  const float* dmb  = (const float*)d_in[11];
  const float* msw  = (const float*)d_in[12];
  const float* rmw  = (const float*)d_in[14];
  const float* rmb  = (const float*)d_in[15];
  const float* qmw  = (const float*)d_in[16];
  const float* qmb  = (const float*)d_in[17];
  const float* rrw  = (const float*)d_in[18];
  const float* rrb  = (const float*)d_in[19];
  const float* rgw  = (const float*)d_in[20];
  const float* rgb  = (const float*)d_in[21];
  const float* qgw  = (const float*)d_in[22];
  const float* qgb  = (const float*)d_in[23];

  char* ws = (char*)d_ws;
  unsigned int* cnt    = (unsigned int*)ws;                       // [0,4096): sync counters
  unsigned short* co   = (unsigned short*)(ws + 4096);            // [B,S,D] bf16
  unsigned short* codm = co + (size_t)B_DIM * S_DIM * D_DIM;      // [B,S,D] bf16
  float* qadd = (float*)(codm + (size_t)B_DIM * S_DIM * D_DIM);   // [T,B,D] f32 (qm+qm_b+rm_b)
  float* addB = qadd + (size_t)T_DIM * B_DIM * D_DIM;             // [B,D]
  float* rrtB = addB + B_DIM * D_DIM;                             // [2,B,D]
  float* denB = rrtB + 2 * B_DIM * D_DIM;                         // [B,8]
  float* pvecB = denB + 256;                                      // [B,8,D]
  unsigned short* ctxb  = (unsigned short*)(pvecB + B_DIM * 8 * D_DIM);
  unsigned short* imgb  = ctxb + (size_t)S_DIM * B_DIM * D_DIM;   // 4.19M elems each
  unsigned short* qob   = imgb + (size_t)S_DIM * B_DIM * D_DIM;   // 393216
  unsigned short* fc1wb = qob + (size_t)T_DIM * B_DIM * D_DIM;    // 262144 each
  unsigned short* fc2wb = fc1wb + D_DIM * D_DIM;
  unsigned short* dmwb  = fc2wb + D_DIM * D_DIM;
  unsigned short* qmwb  = dmwb + D_DIM * D_DIM;

  hipMemsetAsync(cnt, 0, 4096, stream);
  // fp32 -> bf16 for GEMM operands
  cvt_kernel<<<9600, 256, 0, stream>>>(ctx, img, qo, fc1w, fc2w, dmw, qmw,
                                       ctxb, imgb, qob, fc1wb, fc2wb, dmwb, qmwb);
  // co = ctx·fc1^T + img·fc2^T + fc1_b + fc2_b   (K-concat dual GEMM, permuted to [b,s])
  gemm_nt<true, true, true><<<dim3(64, 4), 256, 0, stream>>>(ctxb, imgb, fc1wb, fc2wb, fc1b, fc2b, (void*)co);
  // co_dm = co·dm^T + dm_b
  gemm_nt<false, true, false><<<dim3(64, 4), 256, 0, stream>>>(co, nullptr, dmwb, nullptr, dmb, nullptr, (void*)codm);
  // qadd[t] = q_t·qm^T + qm_b + rm_b   (loop-invariant, fp32 out)
  gemm_nt<false, false, false><<<dim3(6, 4), 256, 0, stream>>>(qob, nullptr, qmwb, nullptr, qmb, rmb, (void*)qadd);
  // sequential scan + final g
  scan_kernel<<<256, 512, 0, stream>>>(co, codm, qadd, addB, rrtB, denB, pvecB, cnt,
                                       msw, rmw, rrw, rrb, qhs, rgw, qgw, rgb, qgb,
                                       (float*)d_out);
}

// Round 3
// 386.599 us; speedup vs baseline: 2.6052x; 2.6052x over previous
//
#include <hip/hip_runtime.h>

// Shapes (fixed by the problem)
#define S_DIM 256
#define B_DIM 32
#define T_DIM 24
#define D_DIM 512

typedef short short8 __attribute__((ext_vector_type(8)));          // bf16x8 MFMA frag
typedef unsigned short ushort8 __attribute__((ext_vector_type(8)));
typedef unsigned short ushort4v __attribute__((ext_vector_type(4)));
typedef float float4v __attribute__((ext_vector_type(4)));

// Coherent (IF-scope, L2-bypassing) data movement — no buffer_wbl2/buffer_inv.
#define ATOM_ST(p, v) __hip_atomic_store((p), (v), __ATOMIC_RELAXED, __HIP_MEMORY_SCOPE_AGENT)
#define ATOM_LD(p)    __hip_atomic_load((p), __ATOMIC_RELAXED, __HIP_MEMORY_SCOPE_AGENT)

__device__ __forceinline__ float bf2f(unsigned short u) {
  union { unsigned int i; float f; } v; v.i = ((unsigned int)u) << 16; return v.f;
}
__device__ __forceinline__ unsigned short f2bf(float f) {
  union { float f; unsigned int i; } v; v.f = f;
  unsigned int i = v.i;
  return (unsigned short)((i + 0x7fffu + ((i >> 16) & 1u)) >> 16);  // RNE
}
// tanh(x) = 1 - 2/(exp2(2*log2e*x)+1); saturates correctly for |x| large.
__device__ __forceinline__ float tanh_fast(float x) {
  float p = __builtin_amdgcn_exp2f(x * 2.885390082f);
  return 1.f - 2.f * __builtin_amdgcn_rcpf(1.f + p);
}

__device__ __forceinline__ void gload_lds16(const void* g, void* l) {
  __builtin_amdgcn_global_load_lds(
      (const __attribute__((address_space(1))) void*)g,
      (__attribute__((address_space(3))) void*)l, 16, 0, 0);
}

// ---------------------------------------------------------------------------
// fp32 -> bf16 pre-pass for the 7 GEMM operands.
// ---------------------------------------------------------------------------
__global__ __launch_bounds__(256)
void cvt_kernel(const float* __restrict__ s0, const float* __restrict__ s1,
                const float* __restrict__ s2, const float* __restrict__ s3,
                const float* __restrict__ s4, const float* __restrict__ s5,
                const float* __restrict__ s6,
                unsigned short* __restrict__ d0, unsigned short* __restrict__ d1,
                unsigned short* __restrict__ d2, unsigned short* __restrict__ d3,
                unsigned short* __restrict__ d4, unsigned short* __restrict__ d5,
                unsigned short* __restrict__ d6)
{
  const int idx = blockIdx.x * 256 + threadIdx.x;
  const float* s; unsigned short* d; int off;
  if (idx < 2097152) {
    off = idx & 1048575;
    if (idx < 1048576) { s = s0; d = d0; } else { s = s1; d = d1; }
  } else if (idx < 2195456) {
    off = idx - 2097152; s = s2; d = d2;
  } else {
    const int k = (idx - 2195456) >> 16;
    off = (idx - 2195456) & 65535;
    switch (k) {
      case 0:  s = s3; d = d3; break;
      case 1:  s = s4; d = d4; break;
      case 2:  s = s5; d = d5; break;
      default: s = s6; d = d6; break;
    }
  }
  const float4v v = ((const float4v*)s)[off];
  ushort4v u;
  u[0] = f2bf(v[0]); u[1] = f2bf(v[1]); u[2] = f2bf(v[2]); u[3] = f2bf(v[3]);
  ((ushort4v*)d)[off] = u;
}

// ---------------------------------------------------------------------------
// NT GEMM: out[m,e] = sum_k A[m,k]*W[e,k] (+bias1[e]+bias2[e], fp32 biases)
// A,W bf16 row-major. PERMUTE: out row = (m&31)*256 + (m>>5)  ((s,b) -> [b,s]).
// m97 recipe: 128x128 tile, BK=32, 4 waves, global_load_lds width-16.
// ---------------------------------------------------------------------------
template<bool DUAL, bool OUT_BF16, bool PERMUTE>
__global__ __launch_bounds__(256)
void gemm_nt(const unsigned short* __restrict__ A1,
             const unsigned short* __restrict__ A2,
             const unsigned short* __restrict__ W1,
             const unsigned short* __restrict__ W2,
             const float* __restrict__ bias1,
             const float* __restrict__ bias2,
             void* __restrict__ out)
{
  __shared__ unsigned short At[128 * 32] __attribute__((aligned(16)));
  __shared__ unsigned short Bt[128 * 32] __attribute__((aligned(16)));

  const int tid  = threadIdx.x;
  const int wid  = tid >> 6;
  const int lane = tid & 63;
  const int bm = blockIdx.x, bn = blockIdx.y;
  const int wm = (wid & 1) * 64, wn = (wid >> 1) * 64;

  float4v acc[4][4];
#pragma unroll
  for (int i = 0; i < 4; ++i)
#pragma unroll
    for (int jj = 0; jj < 4; ++jj) acc[i][jj] = (float4v){0.f, 0.f, 0.f, 0.f};

  const int NK = DUAL ? 32 : 16;
  for (int it = 0; it < NK; ++it) {
    const int kk = it * 32;
    const unsigned short* As = A1;
    const unsigned short* Ws = W1;
    int ks = kk;
    if (DUAL && kk >= 512) { As = A2; Ws = W2; ks = kk - 512; }

    __syncthreads();   // previous iter's LDS reads done before overwrite
#pragma unroll
    for (int i = 0; i < 2; ++i) {
      const int lrow = wid * 32 + i * 16 + (lane >> 2);
      const int kc = (lane & 3) * 8;
      gload_lds16(As + (size_t)(bm * 128 + lrow) * 512 + ks + kc,
                  &At[(wid * 32 + i * 16) * 32]);       // wave-uniform LDS base
      gload_lds16(Ws + (size_t)(bn * 128 + lrow) * 512 + ks + kc,
                  &Bt[(wid * 32 + i * 16) * 32]);
    }
    __syncthreads();   // vmcnt(0) drain + barrier

    short8 fa[4], fb[4];
#pragma unroll
    for (int mi = 0; mi < 4; ++mi)
      fa[mi] = *(const short8*)&At[(wm + mi * 16 + (lane & 15)) * 32 + (lane >> 4) * 8];
#pragma unroll
    for (int ni = 0; ni < 4; ++ni)
      fb[ni] = *(const short8*)&Bt[(wn + ni * 16 + (lane & 15)) * 32 + (lane >> 4) * 8];
#pragma unroll
    for (int mi = 0; mi < 4; ++mi)
#pragma unroll
      for (int ni = 0; ni < 4; ++ni)
        acc[mi][ni] = __builtin_amdgcn_mfma_f32_16x16x32_bf16(fa[mi], fb[ni], acc[mi][ni], 0, 0, 0);
  }

  // epilogue: C/D layout col = lane&15, row = (lane>>4)*4 + reg
#pragma unroll
  for (int mi = 0; mi < 4; ++mi) {
    const int row0 = wm + mi * 16 + (lane >> 4) * 4;
#pragma unroll
    for (int ni = 0; ni < 4; ++ni) {
      const int col = bn * 128 + wn + ni * 16 + (lane & 15);
      float bsum = 0.f;
      if (bias1) bsum += bias1[col];
      if (bias2) bsum += bias2[col];
#pragma unroll
      for (int i = 0; i < 4; ++i) {
        const int m = bm * 128 + row0 + i;
        const int orow = PERMUTE ? ((m & 31) * 256 + (m >> 5)) : m;
        const float v = acc[mi][ni][i] + bsum;
        if (OUT_BF16) ((unsigned short*)out)[(size_t)orow * 512 + col] = f2bf(v);
        else          ((float*)out)[(size_t)orow * 512 + col] = v;
      }
    }
  }
}

// ---------------------------------------------------------------------------
// Scan kernel: 256 blocks = 32 b-groups x 8 blocks. Block (b,j):
//  - owns e-chunk [64j,64j+64) for the rm/rr matvecs (bf16 weights in VGPRs)
//  - owns s-chunk [32j,32j+32) for logits/softmax partials
// Cross-block data moves via relaxed agent-scope atomics (IF-coherent,
// L2-bypassing) -> NO threadfence, NO buffer_wbl2/inv, L2 stays warm.
// Ordering: sc1 store retires vmcnt only when visible at the coherence
// point; __syncthreads drains vmcnt(0) before s_barrier; counter bump is
// relaxed and strictly after. rrtB double-buffered by t&1 (only true
// cross-step race).
// ---------------------------------------------------------------------------
__global__ __launch_bounds__(512)
void scan_kernel(const unsigned short* __restrict__ co,
                 const unsigned short* __restrict__ codm,
                 const float* __restrict__ qadd,
                 float* __restrict__ addB,
                 float* __restrict__ rrtB,   // [2][B][512]
                 float* __restrict__ denB,
                 float* __restrict__ pvecB,
                 unsigned int* __restrict__ cnt,
                 const float* __restrict__ ms_w,
                 const float* __restrict__ rm_w,
                 const float* __restrict__ rr_w,
                 const float* __restrict__ rr_b,
                 const float* __restrict__ qhs,
                 const float* __restrict__ rg_w,
                 const float* __restrict__ qg_w,
                 const float* __restrict__ rg_b,
                 const float* __restrict__ qg_b,
                 float* __restrict__ outg)
{
  __shared__ unsigned short scrS[32 * 520] __attribute__((aligned(16)));  // stage scratch, later cdS[32][512]
  __shared__ float rS[512];
  __shared__ float addS[512] __attribute__((aligned(16)));
  __shared__ float msS[512] __attribute__((aligned(16)));
  __shared__ float partS[512];
  __shared__ float partR[512];
  __shared__ float wS[32];
  __shared__ float rrbS[64];

  const int tid  = threadIdx.x;
  const int wid  = tid >> 6;   // 8 waves
  const int lane = tid & 63;
  const int b = blockIdx.x >> 3;
  const int j = blockIdx.x & 7;
  unsigned int* cntb = cnt + b * 16;   // 64B-spaced counters

  // ---- preload rm_w/rr_w rows [64j,64j+64) into VGPRs (bf16) via LDS bounce.
  // thread (wid,lane) ends holding W[e = 64j+lane][k = 64*wid + 8u + i].
  ushort8 rmp[8], rrp[8];
  for (int pass = 0; pass < 4; ++pass) {
    const float* Wsrc = (pass < 2) ? rm_w : rr_w;
    const int rbase = (pass & 1) * 32;
    for (int r = wid; r < 32; r += 8) {
      const float* src = &Wsrc[(size_t)(j * 64 + rbase + r) * 512 + lane * 8];
      float4v a = *(const float4v*)src;
      float4v c = *(const float4v*)(src + 4);
      ushort8 u8;
#pragma unroll
      for (int i = 0; i < 4; ++i) { u8[i] = f2bf(a[i]); u8[i + 4] = f2bf(c[i]); }
      *(ushort8*)&scrS[r * 520 + lane * 8] = u8;
    }
    __syncthreads();
    if ((lane >> 5) == (pass & 1)) {
      const int rloc = lane & 31;
#pragma unroll
      for (int u = 0; u < 8; ++u) {
        ushort8 v = *(const ushort8*)&scrS[rloc * 520 + wid * 64 + u * 8];
        if (pass < 2) rmp[u] = v; else rrp[u] = v;
      }
    }
    __syncthreads();
  }

  // ---- co_dm s-chunk into LDS (bf16, contiguous rows of 512)
  const size_t gbase = ((size_t)b * 256 + j * 32) * 512;
  for (int idx = tid; idx < 2048; idx += 512)
    *(ushort8*)&scrS[idx * 8] = *(const ushort8*)&codm[gbase + (size_t)idx * 8];
  const unsigned short* cdS = scrS;

  msS[tid] = ms_w[tid];
  if (tid < 64) rrbS[tid] = rr_b[j * 64 + tid];
  rS[tid] = 0.f;
  __syncthreads();

  for (int t = 0; t < T_DIM; ++t) {
    // ---------- matvec: add = r*rm^T (+qadd[t]), rrt = tanh(r*rr^T+rr_b)
    float am = 0.f, ar = 0.f;
#pragma unroll
    for (int u = 0; u < 8; ++u) {
      ushort8 wm8 = rmp[u], wr8 = rrp[u];
#pragma unroll
      for (int i2 = 0; i2 < 8; ++i2) {
        const float rv = rS[wid * 64 + u * 8 + i2];   // wave-uniform broadcast
        am = fmaf(rv, bf2f(wm8[i2]), am);
        ar = fmaf(rv, bf2f(wr8[i2]), ar);
      }
    }
    partS[wid * 64 + lane] = am;
    partR[wid * 64 + lane] = ar;
    __syncthreads();
    if (wid == 0) {
      float s = 0.f;
#pragma unroll
      for (int w2 = 0; w2 < 8; ++w2) s += partS[w2 * 64 + lane];
      s += qadd[((size_t)t * 32 + b) * 512 + j * 64 + lane];
      ATOM_ST(&addB[b * 512 + j * 64 + lane], s);
    } else if (wid == 1) {
      float s = 0.f;
#pragma unroll
      for (int w2 = 0; w2 < 8; ++w2) s += partR[w2 * 64 + lane];
      ATOM_ST(&rrtB[(t & 1) * (B_DIM * 512) + b * 512 + j * 64 + lane],
              tanh_fast(s + rrbS[lane]));
    }
    __syncthreads();   // drains vmcnt(0): sc1 stores visible at IF
    if (tid == 0) {    // sync A: add/rrt chunks published
      __hip_atomic_fetch_add(cntb, 1u, __ATOMIC_RELAXED, __HIP_MEMORY_SCOPE_AGENT);
      const unsigned int tgt = 8u * (2u * (unsigned)t + 1u);
      while (ATOM_LD(cntb) < tgt) __builtin_amdgcn_s_sleep(2);
    }
    __syncthreads();

    // ---------- logits for s-chunk: rows sl = 4*wid..4*wid+3
    addS[tid] = ATOM_LD(&addB[b * 512 + tid]);
    __syncthreads();
#pragma unroll
    for (int q = 0; q < 4; ++q) {
      const int sl = wid * 4 + q;
      ushort8 cd8 = *(const ushort8*)&cdS[sl * 512 + lane * 8];
      float4v a0 = *(const float4v*)&addS[lane * 8];
      float4v a1 = *(const float4v*)&addS[lane * 8 + 4];
      float4v m0 = *(const float4v*)&msS[lane * 8];
      float4v m1 = *(const float4v*)&msS[lane * 8 + 4];
      float acc = 0.f;
#pragma unroll
      for (int i = 0; i < 4; ++i) {
        acc = fmaf(tanh_fast(bf2f(cd8[i]) + a0[i]), m0[i], acc);
        acc = fmaf(tanh_fast(bf2f(cd8[i + 4]) + a1[i]), m1[i], acc);
      }
#pragma unroll
      for (int off = 32; off > 0; off >>= 1) acc += __shfl_xor(acc, off, 64);
      if (lane == 0) wS[sl] = __builtin_amdgcn_exp2f(acc * 1.44269504f);  // exp(logit), max-free
    }
    __syncthreads();

    // ---------- weighted partials: pvec_j[e] = sum_{s chunk} w[s]*co[b,s,e]
    {
      float accv = 0.f;
#pragma unroll 8
      for (int sl = 0; sl < 32; ++sl)
        accv = fmaf(wS[sl], bf2f(co[gbase + (size_t)sl * 512 + tid]), accv);
      ATOM_ST(&pvecB[((size_t)b * 8 + j) * 512 + tid], accv);
      if (tid == 0) {
        float dsum = 0.f;
        for (int sl = 0; sl < 32; ++sl) dsum += wS[sl];
        ATOM_ST(&denB[b * 8 + j], dsum);
      }
    }
    __syncthreads();   // drains vmcnt(0): sc1 stores visible at IF
    if (tid == 0) {    // sync B: pvec/den published
      __hip_atomic_fetch_add(cntb, 1u, __ATOMIC_RELAXED, __HIP_MEMORY_SCOPE_AGENT);
      const unsigned int tgt = 8u * (2u * (unsigned)t + 2u);
      while (ATOM_LD(cntb) < tgt) __builtin_amdgcn_s_sleep(2);
    }
    __syncthreads();

    // ---------- reconstruct r (replicated, identical across the 8 blocks)
    {
      float sum = 0.f;
#pragma unroll
      for (int jj = 0; jj < 8; ++jj)
        sum += ATOM_LD(&pvecB[((size_t)b * 8 + jj) * 512 + tid]);
      float den = 0.f;
#pragma unroll
      for (int jj = 0; jj < 8; ++jj) den += ATOM_LD(&denB[b * 8 + jj]);
      rS[tid] = sum * __builtin_amdgcn_rcpf(den) +
                ATOM_LD(&rrtB[(t & 1) * (B_DIM * 512) + b * 512 + tid]);
    }
    __syncthreads();
  }

  // ---------- g = r*rg^T + rg_b + qhs*qg^T + qg_b, e-chunk [64j,64j+64)
  addS[tid] = qhs[b * 512 + tid];
  __syncthreads();
  {
    const int e = j * 64 + lane;
    const float* rgp = rg_w + (size_t)e * 512 + wid * 64;
    const float* qgp = qg_w + (size_t)e * 512 + wid * 64;
    float acc = 0.f;
#pragma unroll
    for (int u = 0; u < 8; ++u) {
      float4v g0 = *(const float4v*)&rgp[u * 8];
      float4v g1 = *(const float4v*)&rgp[u * 8 + 4];
      float4v q0 = *(const float4v*)&qgp[u * 8];
      float4v q1 = *(const float4v*)&qgp[u * 8 + 4];
#pragma unroll
      for (int i2 = 0; i2 < 4; ++i2) {
        acc = fmaf(rS[wid * 64 + u * 8 + i2],     g0[i2], acc);
        acc = fmaf(rS[wid * 64 + u * 8 + 4 + i2], g1[i2], acc);
        acc = fmaf(addS[wid * 64 + u * 8 + i2],     q0[i2], acc);
        acc = fmaf(addS[wid * 64 + u * 8 + 4 + i2], q1[i2], acc);
      }
    }
    partS[wid * 64 + lane] = acc;
  }
  __syncthreads();
  if (wid == 0) {
    float s = 0.f;
#pragma unroll
    for (int w2 = 0; w2 < 8; ++w2) s += partS[w2 * 64 + lane];
    const int e = j * 64 + lane;
    s += rg_b[e] + qg_b[e];
    outg[b * 512 + e] = s;
  }
}

// ---------------------------------------------------------------------------
extern "C" void kernel_launch(void* const* d_in, const int* in_sizes, int n_in,
                              void* d_out, int out_size, void* d_ws, size_t ws_size,
                              hipStream_t stream)
{
  (void)in_sizes; (void)n_in; (void)out_size; (void)ws_size;
  const float* ctx  = (const float*)d_in[0];
  const float* qo   = (const float*)d_in[2];
  const float* qhs  = (const float*)d_in[3];
  const float* img  = (const float*)d_in[4];
  const float* fc1w = (const float*)d_in[6];
  const float* fc1b = (const float*)d_in[7];
  const float* fc2w = (const float*)d_in[8];
  const float* fc2b = (const float*)d_in[9];
  const float* dmw  = (const float*)d_in[10];
  const float* dmb  = (const float*)d_in[11];
  const float* msw  = (const float*)d_in[12];
  const float* rmw  = (const float*)d_in[14];
  const float* rmb  = (const float*)d_in[15];
  const float* qmw  = (const float*)d_in[16];
  const float* qmb  = (const float*)d_in[17];
  const float* rrw  = (const float*)d_in[18];
  const float* rrb  = (const float*)d_in[19];
  const float* rgw  = (const float*)d_in[20];
  const float* rgb  = (const float*)d_in[21];
  const float* qgw  = (const float*)d_in[22];
  const float* qgb  = (const float*)d_in[23];

  char* ws = (char*)d_ws;
  unsigned int* cnt    = (unsigned int*)ws;                       // [0,4096): sync counters
  unsigned short* co   = (unsigned short*)(ws + 4096);            // [B,S,D] bf16
  unsigned short* codm = co + (size_t)B_DIM * S_DIM * D_DIM;      // [B,S,D] bf16
  float* qadd = (float*)(codm + (size_t)B_DIM * S_DIM * D_DIM);   // [T,B,D] f32 (qm+qm_b+rm_b)
  float* addB = qadd + (size_t)T_DIM * B_DIM * D_DIM;             // [B,D]
  float* rrtB = addB + B_DIM * D_DIM;                             // [2,B,D]
  float* denB = rrtB + 2 * B_DIM * D_DIM;                         // [B,8]
  float* pvecB = denB + 256;                                      // [B,8,D]
  unsigned short* ctxb  = (unsigned short*)(pvecB + B_DIM * 8 * D_DIM);
  unsigned short* imgb  = ctxb + (size_t)S_DIM * B_DIM * D_DIM;   // 4.19M elems each
  unsigned short* qob   = imgb + (size_t)S_DIM * B_DIM * D_DIM;   // 393216
  unsigned short* fc1wb = qob + (size_t)T_DIM * B_DIM * D_DIM;    // 262144 each
  unsigned short* fc2wb = fc1wb + D_DIM * D_DIM;
  unsigned short* dmwb  = fc2wb + D_DIM * D_DIM;
  unsigned short* qmwb  = dmwb + D_DIM * D_DIM;

  hipMemsetAsync(cnt, 0, 4096, stream);
  // fp32 -> bf16 for GEMM operands
  cvt_kernel<<<9600, 256, 0, stream>>>(ctx, img, qo, fc1w, fc2w, dmw, qmw,
                                       ctxb, imgb, qob, fc1wb, fc2wb, dmwb, qmwb);
  // co = ctx·fc1^T + img·fc2^T + fc1_b + fc2_b   (K-concat dual GEMM, permuted to [b,s])
  gemm_nt<true, true, true><<<dim3(64, 4), 256, 0, stream>>>(ctxb, imgb, fc1wb, fc2wb, fc1b, fc2b, (void*)co);
  // co_dm = co·dm^T + dm_b
  gemm_nt<false, true, false><<<dim3(64, 4), 256, 0, stream>>>(co, nullptr, dmwb, nullptr, dmb, nullptr, (void*)codm);
  // qadd[t] = q_t·qm^T + qm_b + rm_b   (loop-invariant, fp32 out)
  gemm_nt<false, false, false><<<dim3(6, 4), 256, 0, stream>>>(qob, nullptr, qmwb, nullptr, qmb, rmb, (void*)qadd);
  // sequential scan + final g
  scan_kernel<<<256, 512, 0, stream>>>(co, codm, qadd, addB, rrtB, denB, pvecB, cnt,
                                       msw, rmw, rrw, rrb, qhs, rgw, qgw, rgb, qgb,
                                       (float*)d_out);
}